// Round 13
// baseline (146.898 us; speedup 1.0000x reference)
//
#include <hip/hip_runtime.h>
#include <hip/hip_bf16.h>
#include <math.h>

// Problem constants (RelativeMultiHeadAttention)
constexpr int S_  = 256;   // query length
constexpr int Mm  = 256;   // memory length
constexpr int Bb  = 8;     // batch
constexpr int Dd  = 512;   // model dim
constexpr int Hh  = 8;     // heads
constexpr int HDd = 64;    // head dim
constexpr int Kk  = 512;   // key length = S + M

typedef unsigned short u16;
typedef short bf16x8 __attribute__((ext_vector_type(8)));
typedef float f32x4  __attribute__((ext_vector_type(4)));

constexpr int LROW = 72;   // LDS staging row stride (shorts)
constexpr int QSTR = 520;  // QR/P LDS row stride (shorts)

// fp32 -> bf16 via HW round-to-nearest-even (v_cvt_pk_bf16_f32 on gfx950)
__device__ __forceinline__ u16 f2b(float f) {
  __hip_bfloat16 h = __float2bfloat16(f);
  u16 b; __builtin_memcpy(&b, &h, 2); return b;
}
__device__ __forceinline__ unsigned int cvt2(float x, float y) {
  __hip_bfloat162 h = __float22bfloat162_rn(make_float2(x, y));
  unsigned int bits; __builtin_memcpy(&bits, &h, 4); return bits;
}
__device__ __forceinline__ float b2f(u16 b) {
  union { unsigned int u; float f; } v; v.u = ((unsigned int)b) << 16;
  return v.f;
}
__device__ __forceinline__ int4 pack8(float4 a, float4 b) {
  int4 r;
  r.x = (int)cvt2(a.x, a.y);
  r.y = (int)cvt2(a.z, a.w);
  r.z = (int)cvt2(b.x, b.y);
  r.w = (int)cvt2(b.z, b.w);
  return r;
}

// 64x64 tile staged by all 256 threads (bf16 / fp32-with-convert)
__device__ __forceinline__ void stage_bf16(u16* dst, const u16* __restrict__ src,
                                           int ld, int tid) {
  const int r = tid >> 3, c = (tid & 7) * 8;
  *(int4*)(dst + r * LROW + c)        = *(const int4*)(src + (size_t)r * ld + c);
  *(int4*)(dst + (r + 32) * LROW + c) = *(const int4*)(src + (size_t)(r + 32) * ld + c);
}
__device__ __forceinline__ void stage_f32(u16* dst, const float* __restrict__ src,
                                          int ld, int tid, int nrow32) {
  const int r = tid >> 3, c = (tid & 7) * 8;
  for (int hh = 0; hh < nrow32; ++hh) {
    const float4 a = *(const float4*)(src + (size_t)(r + 32 * hh) * ld + c);
    const float4 b = *(const float4*)(src + (size_t)(r + 32 * hh) * ld + c + 4);
    *(int4*)(dst + (r + 32 * hh) * LROW + c) = pack8(a, b);
  }
}

// 64x64 MFMA step (wave covers rows wave*16..+16, all 64 cols)
__device__ __forceinline__ void mfma_step(const u16* As, const u16* Bs,
                                          f32x4 (&acc)[4], int wave, int lane) {
  const int r16 = lane & 15, q8 = (lane >> 4) * 8;
#pragma unroll
  for (int ks = 0; ks < 64; ks += 32) {
    const bf16x8 a = *(const bf16x8*)(As + (wave * 16 + r16) * LROW + ks + q8);
#pragma unroll
    for (int nb = 0; nb < 4; ++nb) {
      const bf16x8 b = *(const bf16x8*)(Bs + (nb * 16 + r16) * LROW + ks + q8);
      acc[nb] = __builtin_amdgcn_mfma_f32_16x16x32_bf16(a, b, acc[nb], 0, 0, 0);
    }
  }
}

// ---------------------------------------------------------------------------
// All projections, 128(m) x 64(n) tiles, K+V merged (shared A staging),
// register-pipelined K-loop. 416 blocks. (R8-R12 proven version, unchanged)
// ---------------------------------------------------------------------------
__global__ __launch_bounds__(256) void k_proj(const float* __restrict__ x,
                                              const float* __restrict__ mem,
                                              const float* __restrict__ rel,
                                              const float* __restrict__ Wq,
                                              const float* __restrict__ Wk,
                                              const float* __restrict__ Wv,
                                              const float* __restrict__ Wr,
                                              const float* __restrict__ ub,
                                              const float* __restrict__ vb,
                                              u16* __restrict__ qu,
                                              u16* __restrict__ qv,
                                              u16* __restrict__ kb,
                                              u16* __restrict__ vT,
                                              u16* __restrict__ rT) {
  __shared__ u16 As[128 * LROW], Bs[64 * LROW], Bs2[64 * LROW];
  const int tid = threadIdx.x, wave = tid >> 6, lane = tid & 63;
  const int r16 = lane & 15, q8 = (lane >> 4) * 8, rq = (lane >> 4) * 4;
  const int sr = tid >> 3, scg = (tid & 7) * 8;
  const int bid = blockIdx.x;
  int kind, mt, nt;
  if (bid < 128)      { kind = 0; const int t = bid;       mt = t >> 3; nt = t & 7; }
  else if (bid < 384) { kind = 1; const int t = bid - 128; mt = t >> 3; nt = t & 7; }
  else                { kind = 2; const int t = bid - 384; mt = t >> 3; nt = t & 7; }
  const int m0 = mt * 128, n0 = nt * 64;
  const float *A, *B, *B2 = nullptr;
  if (kind == 0)      { A = x + (size_t)m0 * Dd; B = Wq + (size_t)n0 * Dd; }
  else if (kind == 1) { A = (m0 < Mm * Bb) ? mem + (size_t)m0 * Dd
                                           : x + (size_t)(m0 - Mm * Bb) * Dd;
                        B = Wk + (size_t)n0 * Dd; B2 = Wv + (size_t)n0 * Dd; }
  else                { A = rel + (size_t)m0 * Dd; B = Wr + (size_t)n0 * Dd; }

  f32x4 accK[2][4], accV[2][4];
#pragma unroll
  for (int mi = 0; mi < 2; ++mi)
#pragma unroll
    for (int nb = 0; nb < 4; ++nb) {
      accK[mi][nb] = (f32x4){0.f, 0.f, 0.f, 0.f};
      accV[mi][nb] = (f32x4){0.f, 0.f, 0.f, 0.f};
    }

  // prologue: load k0=0 into regs, write LDS
  float4 fa[8], fb[4], fv[4];
#pragma unroll
  for (int hh = 0; hh < 4; ++hh) {
    fa[2 * hh]     = *(const float4*)(A + (size_t)(sr + 32 * hh) * Dd + scg);
    fa[2 * hh + 1] = *(const float4*)(A + (size_t)(sr + 32 * hh) * Dd + scg + 4);
  }
#pragma unroll
  for (int hh = 0; hh < 2; ++hh) {
    fb[2 * hh]     = *(const float4*)(B + (size_t)(sr + 32 * hh) * Dd + scg);
    fb[2 * hh + 1] = *(const float4*)(B + (size_t)(sr + 32 * hh) * Dd + scg + 4);
  }
  if (kind == 1) {
#pragma unroll
    for (int hh = 0; hh < 2; ++hh) {
      fv[2 * hh]     = *(const float4*)(B2 + (size_t)(sr + 32 * hh) * Dd + scg);
      fv[2 * hh + 1] = *(const float4*)(B2 + (size_t)(sr + 32 * hh) * Dd + scg + 4);
    }
  }
#pragma unroll
  for (int hh = 0; hh < 4; ++hh)
    *(int4*)(As + (sr + 32 * hh) * LROW + scg) = pack8(fa[2 * hh], fa[2 * hh + 1]);
#pragma unroll
  for (int hh = 0; hh < 2; ++hh)
    *(int4*)(Bs + (sr + 32 * hh) * LROW + scg) = pack8(fb[2 * hh], fb[2 * hh + 1]);
  if (kind == 1) {
#pragma unroll
    for (int hh = 0; hh < 2; ++hh)
      *(int4*)(Bs2 + (sr + 32 * hh) * LROW + scg) = pack8(fv[2 * hh], fv[2 * hh + 1]);
  }
  __syncthreads();

  for (int k0 = 0; k0 < Dd; k0 += 64) {
    const bool more = k0 < Dd - 64;
    // ---- issue next tile's global loads ----
    if (more) {
      const int kn = k0 + 64;
#pragma unroll
      for (int hh = 0; hh < 4; ++hh) {
        fa[2 * hh]     = *(const float4*)(A + (size_t)(sr + 32 * hh) * Dd + kn + scg);
        fa[2 * hh + 1] = *(const float4*)(A + (size_t)(sr + 32 * hh) * Dd + kn + scg + 4);
      }
#pragma unroll
      for (int hh = 0; hh < 2; ++hh) {
        fb[2 * hh]     = *(const float4*)(B + (size_t)(sr + 32 * hh) * Dd + kn + scg);
        fb[2 * hh + 1] = *(const float4*)(B + (size_t)(sr + 32 * hh) * Dd + kn + scg + 4);
      }
      if (kind == 1) {
#pragma unroll
        for (int hh = 0; hh < 2; ++hh) {
          fv[2 * hh]     = *(const float4*)(B2 + (size_t)(sr + 32 * hh) * Dd + kn + scg);
          fv[2 * hh + 1] = *(const float4*)(B2 + (size_t)(sr + 32 * hh) * Dd + kn + scg + 4);
        }
      }
    }
    // ---- MFMA on current LDS tile ----
#pragma unroll
    for (int ks = 0; ks < 64; ks += 32) {
      bf16x8 a[2];
#pragma unroll
      for (int mi = 0; mi < 2; ++mi)
        a[mi] = *(const bf16x8*)(As + (wave * 32 + mi * 16 + r16) * LROW + ks + q8);
#pragma unroll
      for (int nb = 0; nb < 4; ++nb) {
        const bf16x8 bk = *(const bf16x8*)(Bs + (nb * 16 + r16) * LROW + ks + q8);
#pragma unroll
        for (int mi = 0; mi < 2; ++mi)
          accK[mi][nb] = __builtin_amdgcn_mfma_f32_16x16x32_bf16(a[mi], bk, accK[mi][nb], 0, 0, 0);
        if (kind == 1) {
          const bf16x8 bv = *(const bf16x8*)(Bs2 + (nb * 16 + r16) * LROW + ks + q8);
#pragma unroll
          for (int mi = 0; mi < 2; ++mi)
            accV[mi][nb] = __builtin_amdgcn_mfma_f32_16x16x32_bf16(a[mi], bv, accV[mi][nb], 0, 0, 0);
        }
      }
    }
    __syncthreads();
    // ---- write next tile ----
    if (more) {
#pragma unroll
      for (int hh = 0; hh < 4; ++hh)
        *(int4*)(As + (sr + 32 * hh) * LROW + scg) = pack8(fa[2 * hh], fa[2 * hh + 1]);
#pragma unroll
      for (int hh = 0; hh < 2; ++hh)
        *(int4*)(Bs + (sr + 32 * hh) * LROW + scg) = pack8(fb[2 * hh], fb[2 * hh + 1]);
      if (kind == 1) {
#pragma unroll
        for (int hh = 0; hh < 2; ++hh)
          *(int4*)(Bs2 + (sr + 32 * hh) * LROW + scg) = pack8(fv[2 * hh], fv[2 * hh + 1]);
      }
      __syncthreads();
    }
  }

  const int h = n0 >> 6;   // one head per block column
  if (kind == 0) {
#pragma unroll
    for (int nb = 0; nb < 4; ++nb) {
      const int hd = nb * 16 + r16, n = n0 + hd;
      const float u = ub[n], v = vb[n];
#pragma unroll
      for (int mi = 0; mi < 2; ++mi)
#pragma unroll
        for (int r = 0; r < 4; ++r) {
          const int m = m0 + wave * 32 + mi * 16 + rq + r;
          const int s = m >> 3, b = m & 7;
          const size_t d = ((size_t)(b * Hh + h) * S_ + s) * HDd + hd;
          qu[d] = f2b(accK[mi][nb][r] + u);
          qv[d] = f2b(accK[mi][nb][r] + v);
        }
    }
  } else if (kind == 1) {
#pragma unroll
    for (int nb = 0; nb < 4; ++nb) {
      const int hd = nb * 16 + r16;
#pragma unroll
      for (int mi = 0; mi < 2; ++mi)
#pragma unroll
        for (int r = 0; r < 4; ++r) {
          const int m = m0 + wave * 32 + mi * 16 + rq + r;
          const int pos = m >> 3, b = m & 7;
          kb[((size_t)(b * Hh + h) * Kk + pos) * HDd + hd] = f2b(accK[mi][nb][r]);
          vT[((size_t)(b * Hh + h) * HDd + hd) * Kk + pos] = f2b(accV[mi][nb][r]);
        }
    }
  } else {
#pragma unroll
    for (int nb = 0; nb < 4; ++nb) {
      const int hd = nb * 16 + r16;
#pragma unroll
      for (int mi = 0; mi < 2; ++mi)
#pragma unroll
        for (int r = 0; r < 4; ++r) {
          const int j = m0 + wave * 32 + mi * 16 + rq + r;
          rT[((size_t)h * Kk + j) * HDd + hd] = f2b(accK[mi][nb][r]);
        }
    }
  }
}

// ---------------------------------------------------------------------------
// Fused attention, ZERO-BARRIER: B-operand fragments loaded DIRECTLY from
// global memory (fragment layout is native to the row-major kb/rT/vT
// buffers: lane reads B[nb*16+(lane&15)][ks+q8..+8] = 16 B). No LDS staging,
// no ds_write of tiles, no __syncthreads at all. Only LDS is QRP (66.5 KB ->
// 2 blocks/CU, 8 waves/CU). All QRP accesses are own-wave rows (QR write,
// gather, P write, PV A-read) -- invariant held since R6.
// Dead tiles (t >= ntiles = q0/64+5) skipped: their scores are fully masked
// (P contribution exactly 0) and their QR cols never gathered -> bit-identical
// to R12 while saving up to 3/8 of the work.
// __launch_bounds__(256,2): cap VGPR at 256 so 2 blocks/CU stay resident.
// ---------------------------------------------------------------------------
__global__ __launch_bounds__(256, 2) void k_attn(const u16* __restrict__ qu,
                                                 const u16* __restrict__ qv,
                                                 const u16* __restrict__ kb,
                                                 const u16* __restrict__ vT,
                                                 const u16* __restrict__ rT,
                                                 u16* __restrict__ y) {
  extern __shared__ u16 lds[];
  u16* QRP = lds;                        // 64 x QSTR = 66,560 B (only LDS)
  const int tid = threadIdx.x, wave = tid >> 6, lane = tid & 63;
  const int q0 = blockIdx.x * 64, bh = blockIdx.y, h = bh & 7, b = bh >> 3;
  const int r16 = lane & 15, q8 = (lane >> 4) * 8, rq = (lane >> 4) * 4;
  const int ntiles = (q0 >> 6) + 5;      // 5..8 live k/j tiles

  // A-fragments straight from global (own-wave rows)
  const u16* qvp = qv + ((size_t)bh * S_ + q0 + wave * 16 + r16) * HDd;
  const bf16x8 av0 = *(const bf16x8*)(qvp + q8);
  const bf16x8 av1 = *(const bf16x8*)(qvp + 32 + q8);
  const u16* qup = qu + ((size_t)bh * S_ + q0 + wave * 16 + r16) * HDd;
  const bf16x8 au0 = *(const bf16x8*)(qup + q8);
  const bf16x8 au1 = *(const bf16x8*)(qup + 32 + q8);

  // per-lane B-fragment base pointers (row = nb*16 + r16 within a tile)
  const u16* rfrag = rT + (size_t)h * Kk * HDd + (size_t)r16 * HDd;   // + (t*64+nb*16)*HDd + ks + q8
  const u16* kfrag = kb + (size_t)bh * Kk * HDd + (size_t)r16 * HDd;
  const u16* vfrag = vT + (size_t)bh * HDd * Kk + (size_t)r16 * Kk;   // row = hd, col = pos

  f32x4 sc[8][4];
  f32x4 o[4];
#pragma unroll
  for (int nb = 0; nb < 4; ++nb) o[nb] = (f32x4){0.f, 0.f, 0.f, 0.f};
  float mx[4] = {-INFINITY, -INFINITY, -INFINITY, -INFINITY};

  // ---- Phase A: QR_t and SC_t per live tile, B-frags direct from global ----
#pragma unroll
  for (int t = 0; t < 8; ++t) if (t < ntiles) {
    // QR_t = qv . rT(t)
    f32x4 c4[4];
#pragma unroll
    for (int nb = 0; nb < 4; ++nb) c4[nb] = (f32x4){0.f, 0.f, 0.f, 0.f};
#pragma unroll
    for (int ks = 0; ks < 64; ks += 32) {
      const bf16x8 a = ks ? av1 : av0;
#pragma unroll
      for (int nb = 0; nb < 4; ++nb) {
        const bf16x8 bb = *(const bf16x8*)(rfrag + (size_t)(t * 64 + nb * 16) * HDd + ks + q8);
        c4[nb] = __builtin_amdgcn_mfma_f32_16x16x32_bf16(a, bb, c4[nb], 0, 0, 0);
      }
    }
#pragma unroll
    for (int nb = 0; nb < 4; ++nb)
#pragma unroll
      for (int r = 0; r < 4; ++r)
        QRP[(wave * 16 + rq + r) * QSTR + t * 64 + nb * 16 + r16] = f2b(c4[nb][r]);

    // SC_t = qu . kb(t)
#pragma unroll
    for (int nb = 0; nb < 4; ++nb) sc[t][nb] = (f32x4){0.f, 0.f, 0.f, 0.f};
#pragma unroll
    for (int ks = 0; ks < 64; ks += 32) {
      const bf16x8 a = ks ? au1 : au0;
#pragma unroll
      for (int nb = 0; nb < 4; ++nb) {
        const bf16x8 bb = *(const bf16x8*)(kfrag + (size_t)(t * 64 + nb * 16) * HDd + ks + q8);
        sc[t][nb] = __builtin_amdgcn_mfma_f32_16x16x32_bf16(a, bb, sc[t][nb], 0, 0, 0);
      }
    }
  }

  // ---- softmax: gather QR + mask + scale; P -> QRP (all own-wave rows) ----
#pragma unroll
  for (int kt = 0; kt < 8; ++kt)
#pragma unroll
    for (int nb = 0; nb < 4; ++nb) {
      const int kk = kt * 64 + nb * 16 + r16;
#pragma unroll
      for (int r = 0; r < 4; ++r) {
        const int ql = wave * 16 + rq + r;
        const int q  = q0 + ql;
        float v;
        if (kk <= q + Mm) {
          const float qr = b2f(QRP[ql * QSTR + (q + Mm - kk)]);
          v = (sc[kt][nb][r] + qr) * 0.125f;   // 1/sqrt(HD) = 1/8
        } else {
          v = -INFINITY;                        // covers dead tiles too
        }
        sc[kt][nb][r] = v;
        mx[r] = fmaxf(mx[r], v);
      }
    }
#pragma unroll
  for (int r = 0; r < 4; ++r)
#pragma unroll
    for (int off = 1; off < 16; off <<= 1)
      mx[r] = fmaxf(mx[r], __shfl_xor(mx[r], off));
  float sum[4] = {0.f, 0.f, 0.f, 0.f};
#pragma unroll
  for (int kt = 0; kt < 8; ++kt)
#pragma unroll
    for (int nb = 0; nb < 4; ++nb)
#pragma unroll
      for (int r = 0; r < 4; ++r) {
        const float p = __expf(sc[kt][nb][r] - mx[r]);
        sc[kt][nb][r] = p;
        sum[r] += p;
      }
#pragma unroll
  for (int r = 0; r < 4; ++r)
#pragma unroll
    for (int off = 1; off < 16; off <<= 1) sum[r] += __shfl_xor(sum[r], off);
  float inv[4];
#pragma unroll
  for (int r = 0; r < 4; ++r) inv[r] = 1.0f / sum[r];
#pragma unroll
  for (int kt = 0; kt < 8; ++kt)
#pragma unroll
    for (int nb = 0; nb < 4; ++nb)
#pragma unroll
      for (int r = 0; r < 4; ++r)
        QRP[(wave * 16 + rq + r) * QSTR + kt * 64 + nb * 16 + r16] =
            f2b(sc[kt][nb][r] * inv[r]);

  // ---- PV: A from QRP (own rows), B = vT frags direct from global ----
#pragma unroll
  for (int t = 0; t < 8; ++t) if (t < ntiles) {
#pragma unroll
    for (int ks = 0; ks < 64; ks += 32) {
      const bf16x8 a = *(const bf16x8*)(QRP + (wave * 16 + r16) * QSTR + t * 64 + ks + q8);
#pragma unroll
      for (int nb = 0; nb < 4; ++nb) {
        const bf16x8 bb = *(const bf16x8*)(vfrag + (size_t)(nb * 16) * Kk + t * 64 + ks + q8);
        o[nb] = __builtin_amdgcn_mfma_f32_16x16x32_bf16(a, bb, o[nb], 0, 0, 0);
      }
    }
  }

#pragma unroll
  for (int nb = 0; nb < 4; ++nb) {
    const int hd = nb * 16 + r16;
#pragma unroll
    for (int r = 0; r < 4; ++r) {
      const int q = q0 + wave * 16 + rq + r;
      y[((size_t)q * Bb + b) * Dd + h * HDd + hd] = f2b(o[nb][r]);
    }
  }
}

// ---------------------------------------------------------------------------
// out = y @ Wo^T, software-pipelined double buffer (R6 proven version).
// 64x64 tiles, 256 threads, grid 8x32. fp32 output.
// ---------------------------------------------------------------------------
__global__ __launch_bounds__(256) void k_out(const u16* __restrict__ y,
                                             const float* __restrict__ Wo,
                                             float* __restrict__ out) {
  __shared__ u16 As[2][64 * LROW], Bs[2][64 * LROW];
  const int tid = threadIdx.x, wave = tid >> 6, lane = tid & 63;
  const int n0 = blockIdx.x * 64, m0 = blockIdx.y * 64;
  const int sr = tid >> 3, scg = (tid & 7) * 8;
  const u16* Ay = y + (size_t)m0 * Dd;
  const float* Bw = Wo + (size_t)n0 * Dd;
  f32x4 acc[4];
#pragma unroll
  for (int i = 0; i < 4; ++i) acc[i] = (f32x4){0.f, 0.f, 0.f, 0.f};

  stage_bf16(As[0], Ay, Dd, tid);
  stage_f32(Bs[0], Bw, Dd, tid, 2);
  __syncthreads();

#pragma unroll
  for (int t = 0; t < 8; ++t) {
    int4 La0, La1;
    float4 f0, f1, f2, f3;
    if (t < 7) {
      const u16* s = Ay + (t + 1) * 64;
      La0 = *(const int4*)(s + (size_t)sr * Dd + scg);
      La1 = *(const int4*)(s + (size_t)(sr + 32) * Dd + scg);
      const float* w = Bw + (t + 1) * 64;
      f0 = *(const float4*)(w + (size_t)sr * Dd + scg);
      f1 = *(const float4*)(w + (size_t)sr * Dd + scg + 4);
      f2 = *(const float4*)(w + (size_t)(sr + 32) * Dd + scg);
      f3 = *(const float4*)(w + (size_t)(sr + 32) * Dd + scg + 4);
    }
    mfma_step(As[t & 1], Bs[t & 1], acc, wave, lane);
    if (t < 7) {
      u16* da = As[(t + 1) & 1];
      *(int4*)(da + sr * LROW + scg)        = La0;
      *(int4*)(da + (sr + 32) * LROW + scg) = La1;
      u16* db = Bs[(t + 1) & 1];
      *(int4*)(db + sr * LROW + scg)        = pack8(f0, f1);
      *(int4*)(db + (sr + 32) * LROW + scg) = pack8(f2, f3);
    }
    __syncthreads();
  }

  const int r16 = lane & 15, rq = (lane >> 4) * 4;
#pragma unroll
  for (int nb = 0; nb < 4; ++nb) {
    const int n = n0 + nb * 16 + r16;
#pragma unroll
    for (int r = 0; r < 4; ++r) {
      const int m = m0 + wave * 16 + rq + r;
      out[(size_t)m * Dd + n] = acc[nb][r];
    }
  }
}

extern "C" void kernel_launch(void* const* d_in, const int* in_sizes, int n_in,
                              void* d_out, int out_size, void* d_ws, size_t ws_size,
                              hipStream_t stream) {
  const float* x    = (const float*)d_in[0];
  const float* mem  = (const float*)d_in[1];
  const float* rel  = (const float*)d_in[2];
  // d_in[3] = attn_mask (recomputed analytically)
  const float* Wq = (const float*)d_in[4];
  const float* Wk = (const float*)d_in[5];
  const float* Wv = (const float*)d_in[6];
  const float* Wr = (const float*)d_in[7];
  const float* Wo = (const float*)d_in[8];
  const float* ub = (const float*)d_in[9];
  const float* vb = (const float*)d_in[10];
  float* out = (float*)d_out;

  u16* qu = (u16*)d_ws;                // 1,048,576
  u16* qv = qu + 1048576;              // 1,048,576
  u16* kb = qv + 1048576;              // 2,097,152
  u16* vT = kb + 2097152;              // 2,097,152
  u16* rT = vT + 2097152;              //   262,144
  u16* yb = rT + 262144;               // 1,048,576
  // total 7.6M u16 = 15.2 MB

  constexpr int ATTN_LDS = 64 * QSTR * (int)sizeof(u16);   // 66,560 B
  (void)hipFuncSetAttribute((const void*)k_attn,
                            hipFuncAttributeMaxDynamicSharedMemorySize, ATTN_LDS);

  k_proj<<<dim3(416),   dim3(256), 0,        stream>>>(x, mem, rel, Wq, Wk, Wv, Wr,
                                                       ub, vb, qu, qv, kb, vT, rT);
  k_attn<<<dim3(4, 64), dim3(256), ATTN_LDS, stream>>>(qu, qv, kb, vT, rT, yb);
  k_out <<<dim3(8, 32), dim3(256), 0,        stream>>>(yb, Wo, out);
}

// Round 14
// 133.163 us; speedup vs baseline: 1.1031x; 1.1031x over previous
//
#include <hip/hip_runtime.h>
#include <hip/hip_bf16.h>
#include <math.h>

// Problem constants (RelativeMultiHeadAttention)
constexpr int S_  = 256;   // query length
constexpr int Mm  = 256;   // memory length
constexpr int Bb  = 8;     // batch
constexpr int Dd  = 512;   // model dim
constexpr int Hh  = 8;     // heads
constexpr int HDd = 64;    // head dim
constexpr int Kk  = 512;   // key length = S + M

typedef unsigned short u16;
typedef short bf16x8 __attribute__((ext_vector_type(8)));
typedef float f32x4  __attribute__((ext_vector_type(4)));

constexpr int LROW = 72;   // LDS staging row stride (shorts)
constexpr int QSTR = 520;  // QR/P LDS row stride (shorts)

// fp32 -> bf16 via HW round-to-nearest-even (v_cvt_pk_bf16_f32 on gfx950)
__device__ __forceinline__ u16 f2b(float f) {
  __hip_bfloat16 h = __float2bfloat16(f);
  u16 b; __builtin_memcpy(&b, &h, 2); return b;
}
__device__ __forceinline__ unsigned int cvt2(float x, float y) {
  __hip_bfloat162 h = __float22bfloat162_rn(make_float2(x, y));
  unsigned int bits; __builtin_memcpy(&bits, &h, 4); return bits;
}
__device__ __forceinline__ float b2f(u16 b) {
  union { unsigned int u; float f; } v; v.u = ((unsigned int)b) << 16;
  return v.f;
}
__device__ __forceinline__ int4 pack8(float4 a, float4 b) {
  int4 r;
  r.x = (int)cvt2(a.x, a.y);
  r.y = (int)cvt2(a.z, a.w);
  r.z = (int)cvt2(b.x, b.y);
  r.w = (int)cvt2(b.z, b.w);
  return r;
}

// 64x64 tile staged by all 256 threads (bf16 / fp32-with-convert)
__device__ __forceinline__ void stage_bf16(u16* dst, const u16* __restrict__ src,
                                           int ld, int tid) {
  const int r = tid >> 3, c = (tid & 7) * 8;
  *(int4*)(dst + r * LROW + c)        = *(const int4*)(src + (size_t)r * ld + c);
  *(int4*)(dst + (r + 32) * LROW + c) = *(const int4*)(src + (size_t)(r + 32) * ld + c);
}
__device__ __forceinline__ void stage_f32(u16* dst, const float* __restrict__ src,
                                          int ld, int tid, int nrow32) {
  const int r = tid >> 3, c = (tid & 7) * 8;
  for (int hh = 0; hh < nrow32; ++hh) {
    const float4 a = *(const float4*)(src + (size_t)(r + 32 * hh) * ld + c);
    const float4 b = *(const float4*)(src + (size_t)(r + 32 * hh) * ld + c + 4);
    *(int4*)(dst + (r + 32 * hh) * LROW + c) = pack8(a, b);
  }
}

// 64x64 MFMA step (wave covers rows wave*16..+16, all 64 cols)
__device__ __forceinline__ void mfma_step(const u16* As, const u16* Bs,
                                          f32x4 (&acc)[4], int wave, int lane) {
  const int r16 = lane & 15, q8 = (lane >> 4) * 8;
#pragma unroll
  for (int ks = 0; ks < 64; ks += 32) {
    const bf16x8 a = *(const bf16x8*)(As + (wave * 16 + r16) * LROW + ks + q8);
#pragma unroll
    for (int nb = 0; nb < 4; ++nb) {
      const bf16x8 b = *(const bf16x8*)(Bs + (nb * 16 + r16) * LROW + ks + q8);
      acc[nb] = __builtin_amdgcn_mfma_f32_16x16x32_bf16(a, b, acc[nb], 0, 0, 0);
    }
  }
}

// ---------------------------------------------------------------------------
// All projections, 128(m) x 64(n) tiles, K+V merged (shared A staging),
// register-pipelined K-loop. 416 blocks. (R8-R12 proven version, unchanged)
// NOTE: for every kind, writer block linear id % 8 == nt == head h, so all
// per-head outputs are written from XCD h (round-robin dispatch heuristic).
// k_attn's grid below is relabeled to read head h from XCD h.
// ---------------------------------------------------------------------------
__global__ __launch_bounds__(256) void k_proj(const float* __restrict__ x,
                                              const float* __restrict__ mem,
                                              const float* __restrict__ rel,
                                              const float* __restrict__ Wq,
                                              const float* __restrict__ Wk,
                                              const float* __restrict__ Wv,
                                              const float* __restrict__ Wr,
                                              const float* __restrict__ ub,
                                              const float* __restrict__ vb,
                                              u16* __restrict__ qu,
                                              u16* __restrict__ qv,
                                              u16* __restrict__ kb,
                                              u16* __restrict__ vT,
                                              u16* __restrict__ rT) {
  __shared__ u16 As[128 * LROW], Bs[64 * LROW], Bs2[64 * LROW];
  const int tid = threadIdx.x, wave = tid >> 6, lane = tid & 63;
  const int r16 = lane & 15, q8 = (lane >> 4) * 8, rq = (lane >> 4) * 4;
  const int sr = tid >> 3, scg = (tid & 7) * 8;
  const int bid = blockIdx.x;
  int kind, mt, nt;
  if (bid < 128)      { kind = 0; const int t = bid;       mt = t >> 3; nt = t & 7; }
  else if (bid < 384) { kind = 1; const int t = bid - 128; mt = t >> 3; nt = t & 7; }
  else                { kind = 2; const int t = bid - 384; mt = t >> 3; nt = t & 7; }
  const int m0 = mt * 128, n0 = nt * 64;
  const float *A, *B, *B2 = nullptr;
  if (kind == 0)      { A = x + (size_t)m0 * Dd; B = Wq + (size_t)n0 * Dd; }
  else if (kind == 1) { A = (m0 < Mm * Bb) ? mem + (size_t)m0 * Dd
                                           : x + (size_t)(m0 - Mm * Bb) * Dd;
                        B = Wk + (size_t)n0 * Dd; B2 = Wv + (size_t)n0 * Dd; }
  else                { A = rel + (size_t)m0 * Dd; B = Wr + (size_t)n0 * Dd; }

  f32x4 accK[2][4], accV[2][4];
#pragma unroll
  for (int mi = 0; mi < 2; ++mi)
#pragma unroll
    for (int nb = 0; nb < 4; ++nb) {
      accK[mi][nb] = (f32x4){0.f, 0.f, 0.f, 0.f};
      accV[mi][nb] = (f32x4){0.f, 0.f, 0.f, 0.f};
    }

  // prologue: load k0=0 into regs, write LDS
  float4 fa[8], fb[4], fv[4];
#pragma unroll
  for (int hh = 0; hh < 4; ++hh) {
    fa[2 * hh]     = *(const float4*)(A + (size_t)(sr + 32 * hh) * Dd + scg);
    fa[2 * hh + 1] = *(const float4*)(A + (size_t)(sr + 32 * hh) * Dd + scg + 4);
  }
#pragma unroll
  for (int hh = 0; hh < 2; ++hh) {
    fb[2 * hh]     = *(const float4*)(B + (size_t)(sr + 32 * hh) * Dd + scg);
    fb[2 * hh + 1] = *(const float4*)(B + (size_t)(sr + 32 * hh) * Dd + scg + 4);
  }
  if (kind == 1) {
#pragma unroll
    for (int hh = 0; hh < 2; ++hh) {
      fv[2 * hh]     = *(const float4*)(B2 + (size_t)(sr + 32 * hh) * Dd + scg);
      fv[2 * hh + 1] = *(const float4*)(B2 + (size_t)(sr + 32 * hh) * Dd + scg + 4);
    }
  }
#pragma unroll
  for (int hh = 0; hh < 4; ++hh)
    *(int4*)(As + (sr + 32 * hh) * LROW + scg) = pack8(fa[2 * hh], fa[2 * hh + 1]);
#pragma unroll
  for (int hh = 0; hh < 2; ++hh)
    *(int4*)(Bs + (sr + 32 * hh) * LROW + scg) = pack8(fb[2 * hh], fb[2 * hh + 1]);
  if (kind == 1) {
#pragma unroll
    for (int hh = 0; hh < 2; ++hh)
      *(int4*)(Bs2 + (sr + 32 * hh) * LROW + scg) = pack8(fv[2 * hh], fv[2 * hh + 1]);
  }
  __syncthreads();

  for (int k0 = 0; k0 < Dd; k0 += 64) {
    const bool more = k0 < Dd - 64;
    // ---- issue next tile's global loads ----
    if (more) {
      const int kn = k0 + 64;
#pragma unroll
      for (int hh = 0; hh < 4; ++hh) {
        fa[2 * hh]     = *(const float4*)(A + (size_t)(sr + 32 * hh) * Dd + kn + scg);
        fa[2 * hh + 1] = *(const float4*)(A + (size_t)(sr + 32 * hh) * Dd + kn + scg + 4);
      }
#pragma unroll
      for (int hh = 0; hh < 2; ++hh) {
        fb[2 * hh]     = *(const float4*)(B + (size_t)(sr + 32 * hh) * Dd + kn + scg);
        fb[2 * hh + 1] = *(const float4*)(B + (size_t)(sr + 32 * hh) * Dd + kn + scg + 4);
      }
      if (kind == 1) {
#pragma unroll
        for (int hh = 0; hh < 2; ++hh) {
          fv[2 * hh]     = *(const float4*)(B2 + (size_t)(sr + 32 * hh) * Dd + kn + scg);
          fv[2 * hh + 1] = *(const float4*)(B2 + (size_t)(sr + 32 * hh) * Dd + kn + scg + 4);
        }
      }
    }
    // ---- MFMA on current LDS tile ----
#pragma unroll
    for (int ks = 0; ks < 64; ks += 32) {
      bf16x8 a[2];
#pragma unroll
      for (int mi = 0; mi < 2; ++mi)
        a[mi] = *(const bf16x8*)(As + (wave * 32 + mi * 16 + r16) * LROW + ks + q8);
#pragma unroll
      for (int nb = 0; nb < 4; ++nb) {
        const bf16x8 bk = *(const bf16x8*)(Bs + (nb * 16 + r16) * LROW + ks + q8);
#pragma unroll
        for (int mi = 0; mi < 2; ++mi)
          accK[mi][nb] = __builtin_amdgcn_mfma_f32_16x16x32_bf16(a[mi], bk, accK[mi][nb], 0, 0, 0);
        if (kind == 1) {
          const bf16x8 bv = *(const bf16x8*)(Bs2 + (nb * 16 + r16) * LROW + ks + q8);
#pragma unroll
          for (int mi = 0; mi < 2; ++mi)
            accV[mi][nb] = __builtin_amdgcn_mfma_f32_16x16x32_bf16(a[mi], bv, accV[mi][nb], 0, 0, 0);
        }
      }
    }
    __syncthreads();
    // ---- write next tile ----
    if (more) {
#pragma unroll
      for (int hh = 0; hh < 4; ++hh)
        *(int4*)(As + (sr + 32 * hh) * LROW + scg) = pack8(fa[2 * hh], fa[2 * hh + 1]);
#pragma unroll
      for (int hh = 0; hh < 2; ++hh)
        *(int4*)(Bs + (sr + 32 * hh) * LROW + scg) = pack8(fb[2 * hh], fb[2 * hh + 1]);
      if (kind == 1) {
#pragma unroll
        for (int hh = 0; hh < 2; ++hh)
          *(int4*)(Bs2 + (sr + 32 * hh) * LROW + scg) = pack8(fv[2 * hh], fv[2 * hh + 1]);
      }
      __syncthreads();
    }
  }

  const int h = n0 >> 6;   // one head per block column
  if (kind == 0) {
#pragma unroll
    for (int nb = 0; nb < 4; ++nb) {
      const int hd = nb * 16 + r16, n = n0 + hd;
      const float u = ub[n], v = vb[n];
#pragma unroll
      for (int mi = 0; mi < 2; ++mi)
#pragma unroll
        for (int r = 0; r < 4; ++r) {
          const int m = m0 + wave * 32 + mi * 16 + rq + r;
          const int s = m >> 3, b = m & 7;
          const size_t d = ((size_t)(b * Hh + h) * S_ + s) * HDd + hd;
          qu[d] = f2b(accK[mi][nb][r] + u);
          qv[d] = f2b(accK[mi][nb][r] + v);
        }
    }
  } else if (kind == 1) {
#pragma unroll
    for (int nb = 0; nb < 4; ++nb) {
      const int hd = nb * 16 + r16;
#pragma unroll
      for (int mi = 0; mi < 2; ++mi)
#pragma unroll
        for (int r = 0; r < 4; ++r) {
          const int m = m0 + wave * 32 + mi * 16 + rq + r;
          const int pos = m >> 3, b = m & 7;
          kb[((size_t)(b * Hh + h) * Kk + pos) * HDd + hd] = f2b(accK[mi][nb][r]);
          vT[((size_t)(b * Hh + h) * HDd + hd) * Kk + pos] = f2b(accV[mi][nb][r]);
        }
    }
  } else {
#pragma unroll
    for (int nb = 0; nb < 4; ++nb) {
      const int hd = nb * 16 + r16;
#pragma unroll
      for (int mi = 0; mi < 2; ++mi)
#pragma unroll
        for (int r = 0; r < 4; ++r) {
          const int j = m0 + wave * 32 + mi * 16 + rq + r;
          rT[((size_t)h * Kk + j) * HDd + hd] = f2b(accK[mi][nb][r]);
        }
    }
  }
}

// ---------------------------------------------------------------------------
// Fused attention: merged-phase, barrier-minimized (R12 proven version),
// with XCD-LOCAL grid relabeling: flat 256-block grid, h = bid & 7 so the
// reader block for head h lands on XCD h (round-robin id%8 placement) --
// the same XCD whose L2 holds qu/qv/kb/vT/rT for that head (writer ids in
// k_proj are == h mod 8 for every kind). Pure relabeling: covered (q0,bh)
// set and all arithmetic identical to R12 -> bit-identical output.
// ---------------------------------------------------------------------------
__global__ __launch_bounds__(256, 1) void k_attn(const u16* __restrict__ qu,
                                                 const u16* __restrict__ qv,
                                                 const u16* __restrict__ kb,
                                                 const u16* __restrict__ vT,
                                                 const u16* __restrict__ rT,
                                                 u16* __restrict__ y) {
  extern __shared__ u16 lds[];
  u16* QRP = lds;                        // 64 x QSTR   (66,560 B)
  u16* VS  = lds + 64 * QSTR;            // 6 x 64 x LROW (27,648 B) vT tiles 0..5
  u16* KR0 = VS + 6 * 64 * LROW;         // 128 x LROW (rT rows 0..63, kb rows 64..127)
  u16* KR1 = KR0 + 128 * LROW;           // 128 x LROW
  const int tid = threadIdx.x, wave = tid >> 6, lane = tid & 63;
  const int bid = blockIdx.x;
  const int h = bid & 7, b = (bid >> 3) & 7, q0 = (bid >> 6) * 64;
  const int bh = b * Hh + h;
  const int r16 = lane & 15, q8 = (lane >> 4) * 8, rq = (lane >> 4) * 4;
  const int sr = tid >> 3, scg = (tid & 7) * 8;    // staging row / col

  // A-fragments straight from global (own-wave rows)
  const u16* qvp = qv + ((size_t)bh * S_ + q0 + wave * 16 + r16) * HDd;
  const bf16x8 av0 = *(const bf16x8*)(qvp + q8);
  const bf16x8 av1 = *(const bf16x8*)(qvp + 32 + q8);
  const u16* qup = qu + ((size_t)bh * S_ + q0 + wave * 16 + r16) * HDd;
  const bf16x8 au0 = *(const bf16x8*)(qup + q8);
  const bf16x8 au1 = *(const bf16x8*)(qup + 32 + q8);

  const u16* rbase = rT + (size_t)h * Kk * HDd;
  const u16* kbase = kb + (size_t)bh * Kk * HDd;
  const u16* vbase = vT + (size_t)bh * HDd * Kk;

  f32x4 sc[8][4];
  f32x4 o[4];
#pragma unroll
  for (int nb = 0; nb < 4; ++nb) o[nb] = (f32x4){0.f, 0.f, 0.f, 0.f};
  float mx[4] = {-INFINITY, -INFINITY, -INFINITY, -INFINITY};

  // prologue: stage rT(0)+kb(0) directly into KR0
  *(int4*)(KR0 + sr * LROW + scg) =
      *(const int4*)(rbase + (size_t)sr * HDd + scg);
  *(int4*)(KR0 + (sr + 32) * LROW + scg) =
      *(const int4*)(rbase + (size_t)(sr + 32) * HDd + scg);
  *(int4*)(KR0 + (64 + sr) * LROW + scg) =
      *(const int4*)(kbase + (size_t)sr * HDd + scg);
  *(int4*)(KR0 + (64 + sr + 32) * LROW + scg) =
      *(const int4*)(kbase + (size_t)(sr + 32) * HDd + scg);
  __syncthreads();

  int4 V6a, V6b, V7a, V7b;   // parked vT tiles 6,7 (written to LDS in phase C)

  // ---- Phase A: 8 jobs, one barrier each ----
#pragma unroll
  for (int t = 0; t < 8; ++t) {
    const u16* buf = (t & 1) ? KR1 : KR0;
    u16* nxt      = (t & 1) ? KR0 : KR1;
    int4 Lr0, Lr1, Lk0, Lk1, Lv0, Lv1;
    if (t < 7) {
      const u16* rs = rbase + (size_t)((t + 1) * 64) * HDd;
      Lr0 = *(const int4*)(rs + (size_t)sr * HDd + scg);
      Lr1 = *(const int4*)(rs + (size_t)(sr + 32) * HDd + scg);
      const u16* ks = kbase + (size_t)((t + 1) * 64) * HDd;
      Lk0 = *(const int4*)(ks + (size_t)sr * HDd + scg);
      Lk1 = *(const int4*)(ks + (size_t)(sr + 32) * HDd + scg);
    }
    if (t < 6) {
      const u16* vs = vbase + t * 64;
      Lv0 = *(const int4*)(vs + (size_t)sr * Kk + scg);
      Lv1 = *(const int4*)(vs + (size_t)(sr + 32) * Kk + scg);
    } else if (t == 6) {
      const u16* vs = vbase + 6 * 64;
      V6a = *(const int4*)(vs + (size_t)sr * Kk + scg);
      V6b = *(const int4*)(vs + (size_t)(sr + 32) * Kk + scg);
    } else {
      const u16* vs = vbase + 7 * 64;
      V7a = *(const int4*)(vs + (size_t)sr * Kk + scg);
      V7b = *(const int4*)(vs + (size_t)(sr + 32) * Kk + scg);
    }

    // QR_t from rT half (rows 0..63)
    f32x4 c4[4];
#pragma unroll
    for (int nb = 0; nb < 4; ++nb) c4[nb] = (f32x4){0.f, 0.f, 0.f, 0.f};
#pragma unroll
    for (int ks = 0; ks < 64; ks += 32) {
      const bf16x8 a = ks ? av1 : av0;
#pragma unroll
      for (int nb = 0; nb < 4; ++nb) {
        const bf16x8 bb = *(const bf16x8*)(buf + (nb * 16 + r16) * LROW + ks + q8);
        c4[nb] = __builtin_amdgcn_mfma_f32_16x16x32_bf16(a, bb, c4[nb], 0, 0, 0);
      }
    }
#pragma unroll
    for (int nb = 0; nb < 4; ++nb)
#pragma unroll
      for (int r = 0; r < 4; ++r)
        QRP[(wave * 16 + rq + r) * QSTR + t * 64 + nb * 16 + r16] = f2b(c4[nb][r]);

    // SC_t from kb half (rows 64..127)
#pragma unroll
    for (int nb = 0; nb < 4; ++nb) sc[t][nb] = (f32x4){0.f, 0.f, 0.f, 0.f};
#pragma unroll
    for (int ks = 0; ks < 64; ks += 32) {
      const bf16x8 a = ks ? au1 : au0;
#pragma unroll
      for (int nb = 0; nb < 4; ++nb) {
        const bf16x8 bb = *(const bf16x8*)(buf + (64 + nb * 16 + r16) * LROW + ks + q8);
        sc[t][nb] = __builtin_amdgcn_mfma_f32_16x16x32_bf16(a, bb, sc[t][nb], 0, 0, 0);
      }
    }

    // stage next rT/kb + this vT
    if (t < 7) {
      *(int4*)(nxt + sr * LROW + scg)             = Lr0;
      *(int4*)(nxt + (sr + 32) * LROW + scg)      = Lr1;
      *(int4*)(nxt + (64 + sr) * LROW + scg)      = Lk0;
      *(int4*)(nxt + (64 + sr + 32) * LROW + scg) = Lk1;
    }
    if (t < 6) {
      u16* vd = VS + t * (64 * LROW);
      *(int4*)(vd + sr * LROW + scg)        = Lv0;
      *(int4*)(vd + (sr + 32) * LROW + scg) = Lv1;
    }
    __syncthreads();
  }

  // ---- softmax: gather QR + mask + scale; P -> QRP (all own-wave) ----
#pragma unroll
  for (int kt = 0; kt < 8; ++kt)
#pragma unroll
    for (int nb = 0; nb < 4; ++nb) {
      const int kk = kt * 64 + nb * 16 + r16;
#pragma unroll
      for (int r = 0; r < 4; ++r) {
        const int ql = wave * 16 + rq + r;
        const int q  = q0 + ql;
        float v;
        if (kk <= q + Mm) {
          const float qr = b2f(QRP[ql * QSTR + (q + Mm - kk)]);
          v = (sc[kt][nb][r] + qr) * 0.125f;   // 1/sqrt(HD) = 1/8
        } else {
          v = -INFINITY;
        }
        sc[kt][nb][r] = v;
        mx[r] = fmaxf(mx[r], v);
      }
    }
#pragma unroll
  for (int r = 0; r < 4; ++r)
#pragma unroll
    for (int off = 1; off < 16; off <<= 1)
      mx[r] = fmaxf(mx[r], __shfl_xor(mx[r], off));
  float sum[4] = {0.f, 0.f, 0.f, 0.f};
#pragma unroll
  for (int kt = 0; kt < 8; ++kt)
#pragma unroll
    for (int nb = 0; nb < 4; ++nb)
#pragma unroll
      for (int r = 0; r < 4; ++r) {
        const float p = __expf(sc[kt][nb][r] - mx[r]);
        sc[kt][nb][r] = p;
        sum[r] += p;
      }
#pragma unroll
  for (int r = 0; r < 4; ++r)
#pragma unroll
    for (int off = 1; off < 16; off <<= 1) sum[r] += __shfl_xor(sum[r], off);
  float inv[4];
#pragma unroll
  for (int r = 0; r < 4; ++r) inv[r] = 1.0f / sum[r];
#pragma unroll
  for (int kt = 0; kt < 8; ++kt)
#pragma unroll
    for (int nb = 0; nb < 4; ++nb)
#pragma unroll
      for (int r = 0; r < 4; ++r)
        QRP[(wave * 16 + rq + r) * QSTR + kt * 64 + nb * 16 + r16] =
            f2b(sc[kt][nb][r] * inv[r]);

  // ---- Phase C: PV. Tiles 0..5 from VS, no barriers. vT6/7 ds_written
  //      from parked regs during t=0,1; one barrier; tiles 6,7. ----
#pragma unroll
  for (int t = 0; t < 6; ++t) {
    if (t == 0) {
      *(int4*)(KR0 + sr * LROW + scg)        = V6a;
      *(int4*)(KR0 + (sr + 32) * LROW + scg) = V6b;
    }
    if (t == 1) {
      *(int4*)(KR1 + sr * LROW + scg)        = V7a;
      *(int4*)(KR1 + (sr + 32) * LROW + scg) = V7b;
    }
    const u16* vs = VS + t * (64 * LROW);
#pragma unroll
    for (int ks = 0; ks < 64; ks += 32) {
      const bf16x8 a = *(const bf16x8*)(QRP + (wave * 16 + r16) * QSTR + t * 64 + ks + q8);
#pragma unroll
      for (int nb = 0; nb < 4; ++nb) {
        const bf16x8 bb = *(const bf16x8*)(vs + (nb * 16 + r16) * LROW + ks + q8);
        o[nb] = __builtin_amdgcn_mfma_f32_16x16x32_bf16(a, bb, o[nb], 0, 0, 0);
      }
    }
  }
  __syncthreads();
#pragma unroll
  for (int t = 6; t < 8; ++t) {
    const u16* vs = (t == 6) ? KR0 : KR1;
#pragma unroll
    for (int ks = 0; ks < 64; ks += 32) {
      const bf16x8 a = *(const bf16x8*)(QRP + (wave * 16 + r16) * QSTR + t * 64 + ks + q8);
#pragma unroll
      for (int nb = 0; nb < 4; ++nb) {
        const bf16x8 bb = *(const bf16x8*)(vs + (nb * 16 + r16) * LROW + ks + q8);
        o[nb] = __builtin_amdgcn_mfma_f32_16x16x32_bf16(a, bb, o[nb], 0, 0, 0);
      }
    }
  }

#pragma unroll
  for (int nb = 0; nb < 4; ++nb) {
    const int hd = nb * 16 + r16;
#pragma unroll
    for (int r = 0; r < 4; ++r) {
      const int q = q0 + wave * 16 + rq + r;
      y[((size_t)q * Bb + b) * Dd + h * HDd + hd] = f2b(o[nb][r]);
    }
  }
}

// ---------------------------------------------------------------------------
// out = y @ Wo^T, software-pipelined double buffer (R6 proven version).
// 64x64 tiles, 256 threads, grid 8x32. fp32 output.
// ---------------------------------------------------------------------------
__global__ __launch_bounds__(256) void k_out(const u16* __restrict__ y,
                                             const float* __restrict__ Wo,
                                             float* __restrict__ out) {
  __shared__ u16 As[2][64 * LROW], Bs[2][64 * LROW];
  const int tid = threadIdx.x, wave = tid >> 6, lane = tid & 63;
  const int n0 = blockIdx.x * 64, m0 = blockIdx.y * 64;
  const int sr = tid >> 3, scg = (tid & 7) * 8;
  const u16* Ay = y + (size_t)m0 * Dd;
  const float* Bw = Wo + (size_t)n0 * Dd;
  f32x4 acc[4];
#pragma unroll
  for (int i = 0; i < 4; ++i) acc[i] = (f32x4){0.f, 0.f, 0.f, 0.f};

  stage_bf16(As[0], Ay, Dd, tid);
  stage_f32(Bs[0], Bw, Dd, tid, 2);
  __syncthreads();

#pragma unroll
  for (int t = 0; t < 8; ++t) {
    int4 La0, La1;
    float4 f0, f1, f2, f3;
    if (t < 7) {
      const u16* s = Ay + (t + 1) * 64;
      La0 = *(const int4*)(s + (size_t)sr * Dd + scg);
      La1 = *(const int4*)(s + (size_t)(sr + 32) * Dd + scg);
      const float* w = Bw + (t + 1) * 64;
      f0 = *(const float4*)(w + (size_t)sr * Dd + scg);
      f1 = *(const float4*)(w + (size_t)sr * Dd + scg + 4);
      f2 = *(const float4*)(w + (size_t)(sr + 32) * Dd + scg);
      f3 = *(const float4*)(w + (size_t)(sr + 32) * Dd + scg + 4);
    }
    mfma_step(As[t & 1], Bs[t & 1], acc, wave, lane);
    if (t < 7) {
      u16* da = As[(t + 1) & 1];
      *(int4*)(da + sr * LROW + scg)        = La0;
      *(int4*)(da + (sr + 32) * LROW + scg) = La1;
      u16* db = Bs[(t + 1) & 1];
      *(int4*)(db + sr * LROW + scg)        = pack8(f0, f1);
      *(int4*)(db + (sr + 32) * LROW + scg) = pack8(f2, f3);
    }
    __syncthreads();
  }

  const int r16 = lane & 15, rq = (lane >> 4) * 4;
#pragma unroll
  for (int nb = 0; nb < 4; ++nb) {
    const int n = n0 + nb * 16 + r16;
#pragma unroll
    for (int r = 0; r < 4; ++r) {
      const int m = m0 + wave * 16 + rq + r;
      out[(size_t)m * Dd + n] = acc[nb][r];
    }
  }
}

extern "C" void kernel_launch(void* const* d_in, const int* in_sizes, int n_in,
                              void* d_out, int out_size, void* d_ws, size_t ws_size,
                              hipStream_t stream) {
  const float* x    = (const float*)d_in[0];
  const float* mem  = (const float*)d_in[1];
  const float* rel  = (const float*)d_in[2];
  // d_in[3] = attn_mask (recomputed analytically)
  const float* Wq = (const float*)d_in[4];
  const float* Wk = (const float*)d_in[5];
  const float* Wv = (const float*)d_in[6];
  const float* Wr = (const float*)d_in[7];
  const float* Wo = (const float*)d_in[8];
  const float* ub = (const float*)d_in[9];
  const float* vb = (const float*)d_in[10];
  float* out = (float*)d_out;

  u16* qu = (u16*)d_ws;                // 1,048,576
  u16* qv = qu + 1048576;              // 1,048,576
  u16* kb = qv + 1048576;              // 2,097,152
  u16* vT = kb + 2097152;              // 2,097,152
  u16* rT = vT + 2097152;              //   262,144
  u16* yb = rT + 262144;               // 1,048,576
  // total 7.6M u16 = 15.2 MB

  // QRP 64xQSTR + VS 6x64xLROW + 2 x 128xLROW dbuf = 158,720 B (<= 160 KiB)
  constexpr int ATTN_LDS =
      (64 * QSTR + 6 * 64 * LROW + 2 * 128 * LROW) * (int)sizeof(u16);
  (void)hipFuncSetAttribute((const void*)k_attn,
                            hipFuncAttributeMaxDynamicSharedMemorySize, ATTN_LDS);

  k_proj<<<dim3(416),   dim3(256), 0,        stream>>>(x, mem, rel, Wq, Wk, Wv, Wr,
                                                       ub, vb, qu, qv, kb, vT, rT);
  k_attn<<<dim3(256),   dim3(256), ATTN_LDS, stream>>>(qu, qv, kb, vT, rT, yb);
  k_out <<<dim3(8, 32), dim3(256), 0,        stream>>>(yb, Wo, out);
}